// Round 14
// baseline (1479.827 us; speedup 1.0000x reference)
//
#include <hip/hip_runtime.h>

// StructuredLSNN v14: no readlane anywhere (RL measured ~8 cyc/instr — v10/v12/v13
// all fit 640 cyc/step on RL delivery). New delivery:
//  wv0 producer: LDS round-trip (write row q, read it back via 16 uniform b128)
//     -> ~400 cyc/step (256-cyc exact chain + ~130 DS turnaround).
//  wv1-3 GEMM lane=t: state row in per-lane VGPRs (16 b128/chunk), weights are
//     wave-uniform global loads (broadcast), unroll-2 a/b prefetch hides L2 lat
//     under the 256-cyc dependent chain. Raw acc -> padded cur[t][h] LDS tile.
//  LIF lane=h, same wave as its cur columns (no cross-wave dep): bias added here
//     (cur = fadd(acc,bias), same rounding as the absmax=0 kernel).
// One barrier/chunk. All FMA-chain k-orders and LIF scalar ops byte-identical.

#define TT 4096
#define NBATCH 256
#define HH 192
#define CS 64
#define NC (TT / CS)
#define STS 68    // st row stride (floats): banks (4q+lane)%32, b128-aligned (272B)
#define CTS 193   // cur row stride: banks (t+h)%32 -> 2-way (free)

#define FMA4(WQ, SQ) \
    acc = fmaf(WQ.x, SQ.x, acc); \
    acc = fmaf(WQ.y, SQ.y, acc); \
    acc = fmaf(WQ.z, SQ.z, acc); \
    acc = fmaf(WQ.w, SQ.w, acc);

#define CHAIN64(P) \
    FMA4(P##0, s0)   FMA4(P##1, s1)   FMA4(P##2, s2)   FMA4(P##3, s3) \
    FMA4(P##4, s4)   FMA4(P##5, s5)   FMA4(P##6, s6)   FMA4(P##7, s7) \
    FMA4(P##8, s8)   FMA4(P##9, s9)   FMA4(P##10, s10) FMA4(P##11, s11) \
    FMA4(P##12, s12) FMA4(P##13, s13) FMA4(P##14, s14) FMA4(P##15, s15)

#define LD16(P, SRC) \
    P##0 = (SRC)[0];   P##1 = (SRC)[1];   P##2 = (SRC)[2];   P##3 = (SRC)[3]; \
    P##4 = (SRC)[4];   P##5 = (SRC)[5];   P##6 = (SRC)[6];   P##7 = (SRC)[7]; \
    P##8 = (SRC)[8];   P##9 = (SRC)[9];   P##10 = (SRC)[10]; P##11 = (SRC)[11]; \
    P##12 = (SRC)[12]; P##13 = (SRC)[13]; P##14 = (SRC)[14]; P##15 = (SRC)[15];

// producer: exact chain, write row q, read it back (uniform broadcast b128)
#define BUILD_CHUNK(JJ, SEL) { \
    float* stc = &st[SEL][0]; \
    const float* xc = xb + (JJ) * CS; \
    for (int q = 0; q < CS; ++q) { \
        const float xq = xc[q]; \
        float acc = 0.f; \
        CHAIN64(w) \
        const float ns = __fadd_rn(acc, __fmul_rn(bi, xq)); \
        stc[q * STS + lane] = ns; \
        const float4* rb = (const float4*)(stc + q * STS); \
        LD16(s, rb) \
    } }

// GEMM (lane=t) + LIF (lane=h), both on waves 1-3
#define GEMM_LIF_CHUNK(JJ) { \
    const float4* srow = (const float4*)(&st[(JJ) & 1][0] + lane * STS); \
    LD16(s, srow) \
    const float4* wrow = (const float4*)(enc_w + (size_t)hbase * 64); \
    float4 a0,a1,a2,a3,a4,a5,a6,a7,a8,a9,a10,a11,a12,a13,a14,a15; \
    float4 b0,b1,b2,b3,b4,b5,b6,b7,b8,b9,b10,b11,b12,b13,b14,b15; \
    LD16(a, wrow) \
    for (int hh = 0; hh < 64; hh += 2) { \
        LD16(b, wrow + (size_t)(hh + 1) * 16) \
        float acc = 0.f; \
        CHAIN64(a) \
        cur[lane * CTS + hbase + hh] = acc; \
        if (hh + 2 < 64) { LD16(a, wrow + (size_t)(hh + 2) * 16) } \
        acc = 0.f; \
        CHAIN64(b) \
        cur[lane * CTS + hbase + hh + 1] = acc; \
    } \
    float* o = out1 + ((size_t)b * TT + (size_t)(JJ) * CS) * HH + hc; \
    const float* crow = cur + hc; \
    _Pragma("unroll 8") \
    for (int t = 0; t < CS; ++t) { \
        const float cv = __fadd_rn(crow[t * CTS], biasv); \
        mem = __fadd_rn(__fmul_rn(0.9f, mem), cv); \
        const float sv = (mem > 1.0f) ? 1.0f : 0.0f; \
        o[(size_t)t * HH] = sv; \
        mem = __fmul_rn(mem, __fsub_rn(1.0f, sv)); \
        cnt += sv; \
    } }

__global__ __launch_bounds__(256, 1) void lsnn_fused(
    const float* __restrict__ x,
    const float* __restrict__ A,
    const float* __restrict__ Bv,
    const float* __restrict__ enc_w,
    const float* __restrict__ enc_b,
    const float* __restrict__ ro_w,
    const float* __restrict__ ro_b,
    float* __restrict__ out0,
    float* __restrict__ out1)
{
    __shared__ __align__(16) float st[2][CS * STS];   // 34.8 KB
    __shared__ __align__(16) float cur[CS * CTS];     // 49.4 KB
    __shared__ __align__(16) float xb[TT];            // 16.4 KB
    __shared__ float rate[HH];

    const int tid = threadIdx.x;
    const int b = blockIdx.x;
    const int lane = tid & 63;
    const int wv = tid >> 6;                // 0..3 (one wave per SIMD)
    const int hbase = (wv > 0) ? (wv - 1) * 64 : 0;
    const int hc = hbase + lane;            // LIF row (waves 1-3)

    // ---- stage x[b][:] ----
    {
        const float4* xs = (const float4*)(x + (size_t)b * TT);
        float4* xd = (float4*)xb;
        for (int e = tid; e < TT / 4; e += 256) xd[e] = xs[e];
    }

    // ---- per-role register state ----
    float4 s0,s1,s2,s3,s4,s5,s6,s7,s8,s9,s10,s11,s12,s13,s14,s15;
    float4 w0,w1,w2,w3,w4,w5,w6,w7,w8,w9,w10,w11,w12,w13,w14,w15;
    float bi = 0.f;
    if (wv == 0) {                          // producer: A row + zero state
        const float4* r4 = (const float4*)(A + (size_t)lane * 64);
        LD16(w, r4)
        bi = Bv[lane];
        const float4 z = {0.f, 0.f, 0.f, 0.f};
        s0=z; s1=z; s2=z; s3=z; s4=z; s5=z; s6=z; s7=z;
        s8=z; s9=z; s10=z; s11=z; s12=z; s13=z; s14=z; s15=z;
    }
    const float biasv = (wv > 0) ? enc_b[hc] : 0.f;

    float mem = 0.f, cnt = 0.f;

    __syncthreads();                        // xb staged
    if (wv == 0) BUILD_CHUNK(0, 0)
    __syncthreads();                        // chunk 0 ready

    for (int j = 0; j < NC; ++j) {
        if (wv == 0) {
            if (j + 1 < NC) BUILD_CHUNK(j + 1, (j + 1) & 1)
        } else {
            GEMM_LIF_CHUNK(j)
        }
        __syncthreads();
    }

    // ---- rate + readout ----
    if (wv > 0) rate[hc] = cnt * (1.0f / 4096.0f);   // exact
    __syncthreads();
    if (tid < 10) {
        float acc = 0.f;
        for (int k = 0; k < HH; ++k) acc = fmaf(ro_w[tid * HH + k], rate[k], acc);
        out0[b * 10 + tid] = __fadd_rn(acc, ro_b[tid]);
    }
}

extern "C" void kernel_launch(void* const* d_in, const int* in_sizes, int n_in,
                              void* d_out, int out_size, void* d_ws, size_t ws_size,
                              hipStream_t stream) {
    (void)out_size; (void)d_ws; (void)ws_size;
    // size-based input mapping (all seven sizes unique)
    // x:1048576  enc_w:12288  enc_b:192  ro_w:1920  ro_b:10  A:4096  B:64
    const void* px = nullptr; const void* pew = nullptr; const void* peb = nullptr;
    const void* prw = nullptr; const void* prb = nullptr; const void* pA = nullptr;
    const void* pB = nullptr;
    for (int i = 0; i < n_in; ++i) {
        switch (in_sizes[i]) {
            case 1048576: px  = d_in[i]; break;
            case 12288:   pew = d_in[i]; break;
            case 192:     peb = d_in[i]; break;
            case 1920:    prw = d_in[i]; break;
            case 10:      prb = d_in[i]; break;
            case 4096:    pA  = d_in[i]; break;
            case 64:      pB  = d_in[i]; break;
            default: break;
        }
    }
    if (!px || !pew || !peb || !prw || !prb || !pA || !pB) {
        px = d_in[0]; pew = d_in[1]; peb = d_in[2];
        prw = d_in[3]; prb = d_in[4]; pA = d_in[5]; pB = d_in[6];
    }
    const float* x     = (const float*)px;
    const float* enc_w = (const float*)pew;
    const float* enc_b = (const float*)peb;
    const float* ro_w  = (const float*)prw;
    const float* ro_b  = (const float*)prb;
    const float* A     = (const float*)pA;
    const float* Bv    = (const float*)pB;
    float* out0 = (float*)d_out;
    float* out1 = out0 + NBATCH * 10;

    lsnn_fused<<<NBATCH, 256, 0, stream>>>(x, A, Bv, enc_w, enc_b, ro_w, ro_b, out0, out1);
}